// Round 11
// baseline (478.089 us; speedup 1.0000x reference)
//
#include <hip/hip_runtime.h>
#include <hip/hip_fp16.h>

#define N_NODES 200000
#define N_EDGES 6400000
#define IN_FEAT 128
#define HIDDEN  16

// ---- block-local LDS bucket sort -> dense per-block runs + offset table ----
#define RN 512
#define CSHIFT 9
#define NC 391                 // 391*512 = 200192 >= N_NODES
#define CAPB 18432             // sorted-window cap per bucket (mean 16368, +16 sigma)
#define SRC_MASK 0x3FFFFu      // 18 bits, N_NODES < 262144
#define SB1 8192               // edges per cscat block
#define NBLK 782               // ceil(N_EDGES / SB1); last block n = 2048
#define TW 392                 // table row width (391 buckets + sentinel)
#define NSLOT (NC * (RN + 1))  // boffs slots; slot = node + (node>>CSHIFT)

typedef float v4f __attribute__((ext_vector_type(4)));
typedef _Float16 f16x8 __attribute__((ext_vector_type(8)));
typedef float f32x4 __attribute__((ext_vector_type(4)));

// ------- 1. block-local bucket sort: dense 32KB dump + u16 offset table -------

__global__ __launch_bounds__(512) void k_cscat(const int* __restrict__ row,
                                               const int* __restrict__ col,
                                               unsigned short* __restrict__ table,
                                               unsigned* __restrict__ tmp1) {
    __shared__ unsigned cnt[512], cur[512], s[512];
    __shared__ unsigned buf[SB1];               // 32 KB
    const long long e0 = (long long)blockIdx.x * SB1;
    long long rem = (long long)N_EDGES - e0;
    const int n = rem > SB1 ? SB1 : (int)rem;   // multiple of 4
    const int t = threadIdx.x;
    cnt[t] = 0u;
    __syncthreads();

    // count pass (col only, int4)
    const int4* c4 = (const int4*)(col + e0);
    for (int i = t; i < n / 4; i += 512) {
        int4 v = c4[i];
        atomicAdd(&cnt[(unsigned)v.x >> CSHIFT], 1u);
        atomicAdd(&cnt[(unsigned)v.y >> CSHIFT], 1u);
        atomicAdd(&cnt[(unsigned)v.z >> CSHIFT], 1u);
        atomicAdd(&cnt[(unsigned)v.w >> CSHIFT], 1u);
    }
    __syncthreads();

    // inclusive scan over 512 -> exclusive bases
    unsigned cv = cnt[t];
    s[t] = cv;
    __syncthreads();
    #pragma unroll
    for (int d = 1; d < 512; d <<= 1) {
        unsigned add = (t >= d) ? s[t - d] : 0u;
        __syncthreads();
        s[t] += add;
        __syncthreads();
    }
    unsigned base = s[t] - cv;                  // exclusive prefix
    cur[t] = base;
    if (t < TW) table[(size_t)blockIdx.x * TW + t] = (unsigned short)base;  // t=391: = n
    __syncthreads();

    // LDS scatter pass (re-read col/row, L2-hot)
    for (int i = t; i < n; i += 512) {
        unsigned c = (unsigned)col[e0 + i];
        unsigned sr = (unsigned)row[e0 + i];
        unsigned b = c >> CSHIFT;
        unsigned pos = atomicAdd(&cur[b], 1u);
        buf[pos] = ((c & (RN - 1u)) << 18) | sr;
    }
    __syncthreads();

    // dense coalesced dump into the block's private region
    uint4* dst = (uint4*)(tmp1 + e0);
    const uint4* src4 = (const uint4*)buf;
    for (int i = t; i < n / 4; i += 512) dst[i] = src4[i];
}

// ------- 2. per-bucket sort: gather 782 runs -> node-CSR + boffs + dinv -------
// boffs slot layout: bucket r owns slots [r*(RN+1), r*(RN+1)+RN]; slot = node + (node>>CSHIFT)

__global__ __launch_bounds__(1024) void k_bsort(const unsigned* __restrict__ tmp1,
                                                const unsigned short* __restrict__ table,
                                                unsigned* __restrict__ boffs,
                                                float* __restrict__ dinv,
                                                unsigned* __restrict__ sorted) {
    __shared__ unsigned dcnt[RN], dcur[RN], sscan[RN];
    const int r = blockIdx.x;
    const unsigned lo = (unsigned)r * CAPB;
    const unsigned node0 = (unsigned)r * RN;
    const unsigned slot0 = (unsigned)r * (RN + 1);
    const int t = threadIdx.x;

    // this thread's run (one per cscat block); no arrays (rule #20)
    unsigned rbase = 0, rend = 0;
    long long gbase = 0;
    if (t < NBLK) {
        rbase = table[(size_t)t * TW + r];
        rend  = table[(size_t)t * TW + r + 1];
        gbase = (long long)t * SB1;
    }
    if (t < RN) dcnt[t] = 0u;
    __syncthreads();

    for (unsigned j = rbase; j < rend; ++j)
        atomicAdd(&dcnt[tmp1[gbase + j] >> 18], 1u);
    __syncthreads();

    unsigned c = 0;
    if (t < RN) { c = dcnt[t]; sscan[t] = c; }
    __syncthreads();
    #pragma unroll
    for (int d = 1; d < RN; d <<= 1) {
        unsigned add = 0;
        if (t < RN && t >= d) add = sscan[t - d];
        __syncthreads();
        if (t < RN) sscan[t] += add;
        __syncthreads();
    }
    if (t < RN) {
        unsigned excl = sscan[t] - c;
        dcur[t] = excl;
        boffs[slot0 + t] = lo + excl;
        unsigned node = node0 + t;
        if (node < N_NODES) dinv[node] = rsqrtf((float)c + 1.0f);   // +1 self-loop
    }
    if (t == RN - 1) boffs[slot0 + RN] = lo + sscan[t];
    __syncthreads();

    for (unsigned j = rbase; j < rend; ++j) {
        unsigned p = tmp1[gbase + j];
        unsigned pos = atomicAdd(&dcur[p >> 18], 1u);
        sorted[lo + pos] = p & SRC_MASK;
    }
}

// ---------------- layer-1 GEMM via MFMA: h16 = dinv .* (x @ W1), fp16 ----------------

__global__ __launch_bounds__(256) void k_gemm1(const float* __restrict__ x,
                                               const float* __restrict__ W1,
                                               const float* __restrict__ dinv,
                                               __half* __restrict__ h16) {
    const int wave = (blockIdx.x * 256 + threadIdx.x) >> 6;   // tile id
    const int lane = threadIdx.x & 63;
    const int m16 = lane & 15;
    const int quad = lane >> 4;
    if (wave * 16 >= N_NODES) return;

    f16x8 bf[4];
    #pragma unroll
    for (int kb = 0; kb < 4; ++kb)
        #pragma unroll
        for (int j = 0; j < 8; ++j)
            bf[kb][j] = (_Float16)W1[(kb * 32 + quad * 8 + j) * HIDDEN + m16];

    const int node0 = wave * 16;
    const float* xrow = x + (size_t)(node0 + m16) * IN_FEAT + quad * 8;
    f32x4 acc = {0.f, 0.f, 0.f, 0.f};
    #pragma unroll
    for (int kb = 0; kb < 4; ++kb) {
        const v4f* p = (const v4f*)(xrow + kb * 32);
        v4f u0 = p[0], u1 = p[1];
        f16x8 af;
        af[0] = (_Float16)u0.x; af[1] = (_Float16)u0.y;
        af[2] = (_Float16)u0.z; af[3] = (_Float16)u0.w;
        af[4] = (_Float16)u1.x; af[5] = (_Float16)u1.y;
        af[6] = (_Float16)u1.z; af[7] = (_Float16)u1.w;
        acc = __builtin_amdgcn_mfma_f32_16x16x32_f16(af, bf[kb], acc, 0, 0, 0);
    }
    #pragma unroll
    for (int r = 0; r < 4; ++r) {
        int node = node0 + quad * 4 + r;
        h16[(size_t)node * HIDDEN + m16] = __float2half(dinv[node] * acc[r]);
    }
}

// ------- layer-1 CSR aggregation: 8 lanes/node, uint2 pair-gather (16 edges in flight) -------
// lane l: q=l&3 owns features 4q..4q+3; eh=l>>2 owns edges of parity eh within each pair.

__global__ __launch_bounds__(256) void k_agg1(const unsigned* __restrict__ sorted,
                                              const unsigned* __restrict__ boffs,
                                              const uint2* __restrict__ h16v,
                                              const float* __restrict__ dinv,
                                              const float* __restrict__ b1,
                                              const float* __restrict__ W2,
                                              float* __restrict__ tp) {
    const unsigned tid = blockIdx.x * 256 + threadIdx.x;
    const unsigned node = tid >> 3;
    const int l = tid & 7;
    const int q = l & 3;
    const int eh = l >> 2;
    if (node >= N_NODES) return;

    const unsigned slot = node + (node >> CSHIFT);
    unsigned e = boffs[slot];
    const unsigned o1 = boffs[slot + 1];
    float a0 = 0.f, a1 = 0.f, a2 = 0.f, a3 = 0.f;

    unsigned nb0, nb1, nb2, nb3, nb4, nb5, nb6, nb7;
    bool have = (e + 16 <= o1);
    if (have) {
        nb0 = sorted[e +  0 + eh]; nb1 = sorted[e +  2 + eh];
        nb2 = sorted[e +  4 + eh]; nb3 = sorted[e +  6 + eh];
        nb4 = sorted[e +  8 + eh]; nb5 = sorted[e + 10 + eh];
        nb6 = sorted[e + 12 + eh]; nb7 = sorted[e + 14 + eh];
    }
    while (have) {
        unsigned cb0 = nb0, cb1 = nb1, cb2 = nb2, cb3 = nb3;
        unsigned cb4 = nb4, cb5 = nb5, cb6 = nb6, cb7 = nb7;
        e += 16;
        have = (e + 16 <= o1);
        if (have) {
            nb0 = sorted[e +  0 + eh]; nb1 = sorted[e +  2 + eh];
            nb2 = sorted[e +  4 + eh]; nb3 = sorted[e +  6 + eh];
            nb4 = sorted[e +  8 + eh]; nb5 = sorted[e + 10 + eh];
            nb6 = sorted[e + 12 + eh]; nb7 = sorted[e + 14 + eh];
        }
        uint2 v0 = h16v[(size_t)cb0 * 4 + q];
        uint2 v1 = h16v[(size_t)cb1 * 4 + q];
        uint2 v2 = h16v[(size_t)cb2 * 4 + q];
        uint2 v3 = h16v[(size_t)cb3 * 4 + q];
        uint2 v4 = h16v[(size_t)cb4 * 4 + q];
        uint2 v5 = h16v[(size_t)cb5 * 4 + q];
        uint2 v6 = h16v[(size_t)cb6 * 4 + q];
        uint2 v7 = h16v[(size_t)cb7 * 4 + q];
        float2 f, g;
        f = __half22float2(*(const __half2*)&v0.x); g = __half22float2(*(const __half2*)&v0.y);
        a0 += f.x; a1 += f.y; a2 += g.x; a3 += g.y;
        f = __half22float2(*(const __half2*)&v1.x); g = __half22float2(*(const __half2*)&v1.y);
        a0 += f.x; a1 += f.y; a2 += g.x; a3 += g.y;
        f = __half22float2(*(const __half2*)&v2.x); g = __half22float2(*(const __half2*)&v2.y);
        a0 += f.x; a1 += f.y; a2 += g.x; a3 += g.y;
        f = __half22float2(*(const __half2*)&v3.x); g = __half22float2(*(const __half2*)&v3.y);
        a0 += f.x; a1 += f.y; a2 += g.x; a3 += g.y;
        f = __half22float2(*(const __half2*)&v4.x); g = __half22float2(*(const __half2*)&v4.y);
        a0 += f.x; a1 += f.y; a2 += g.x; a3 += g.y;
        f = __half22float2(*(const __half2*)&v5.x); g = __half22float2(*(const __half2*)&v5.y);
        a0 += f.x; a1 += f.y; a2 += g.x; a3 += g.y;
        f = __half22float2(*(const __half2*)&v6.x); g = __half22float2(*(const __half2*)&v6.y);
        a0 += f.x; a1 += f.y; a2 += g.x; a3 += g.y;
        f = __half22float2(*(const __half2*)&v7.x); g = __half22float2(*(const __half2*)&v7.y);
        a0 += f.x; a1 += f.y; a2 += g.x; a3 += g.y;
    }
    if (e + 8 <= o1) {                           // mid block: 8 edges, 4 pair-slots
        unsigned cb0 = sorted[e + 0 + eh], cb1 = sorted[e + 2 + eh];
        unsigned cb2 = sorted[e + 4 + eh], cb3 = sorted[e + 6 + eh];
        uint2 v0 = h16v[(size_t)cb0 * 4 + q];
        uint2 v1 = h16v[(size_t)cb1 * 4 + q];
        uint2 v2 = h16v[(size_t)cb2 * 4 + q];
        uint2 v3 = h16v[(size_t)cb3 * 4 + q];
        float2 f, g;
        f = __half22float2(*(const __half2*)&v0.x); g = __half22float2(*(const __half2*)&v0.y);
        a0 += f.x; a1 += f.y; a2 += g.x; a3 += g.y;
        f = __half22float2(*(const __half2*)&v1.x); g = __half22float2(*(const __half2*)&v1.y);
        a0 += f.x; a1 += f.y; a2 += g.x; a3 += g.y;
        f = __half22float2(*(const __half2*)&v2.x); g = __half22float2(*(const __half2*)&v2.y);
        a0 += f.x; a1 += f.y; a2 += g.x; a3 += g.y;
        f = __half22float2(*(const __half2*)&v3.x); g = __half22float2(*(const __half2*)&v3.y);
        a0 += f.x; a1 += f.y; a2 += g.x; a3 += g.y;
        e += 8;
    }
    for (; e < o1; ++e) {                        // scalar tail: eh==0 half only
        if (eh == 0) {
            unsigned s = sorted[e];
            uint2 v = h16v[(size_t)s * 4 + q];
            float2 f = __half22float2(*(const __half2*)&v.x);
            float2 g = __half22float2(*(const __half2*)&v.y);
            a0 += f.x; a1 += f.y; a2 += g.x; a3 += g.y;
        }
    }

    // merge edge halves (lanes l and l^4 hold same features, complementary edges)
    a0 += __shfl_xor(a0, 4, 8);
    a1 += __shfl_xor(a1, 4, 8);
    a2 += __shfl_xor(a2, 4, 8);
    a3 += __shfl_xor(a3, 4, 8);

    // self-loop + node2 epilogue
    uint2 vs = h16v[(size_t)node * 4 + q];
    float2 s01 = __half22float2(*(const __half2*)&vs.x);
    float2 s23 = __half22float2(*(const __half2*)&vs.y);
    float di = dinv[node];
    float p0 = fmaf(di, a0 + s01.x, b1[4 * q + 0]);
    float p1 = fmaf(di, a1 + s01.y, b1[4 * q + 1]);
    float p2 = fmaf(di, a2 + s23.x, b1[4 * q + 2]);
    float p3 = fmaf(di, a3 + s23.y, b1[4 * q + 3]);
    float r = fmaxf(p0, 0.f) * W2[4 * q + 0] + fmaxf(p1, 0.f) * W2[4 * q + 1]
            + fmaxf(p2, 0.f) * W2[4 * q + 2] + fmaxf(p3, 0.f) * W2[4 * q + 3];
    r += __shfl_xor(r, 2, 8);
    r += __shfl_xor(r, 1, 8);
    if (l == 0) tp[node] = di * r;
}

// ------- layer-2 CSR aggregation (1 lane/node, 8-deep) + fused finalize -------

__global__ __launch_bounds__(256) void k_agg2(const unsigned* __restrict__ sorted,
                                              const unsigned* __restrict__ boffs,
                                              const float* __restrict__ tp,
                                              const float* __restrict__ dinv,
                                              const float* __restrict__ b2,
                                              float* __restrict__ out) {
    const unsigned node = blockIdx.x * 256 + threadIdx.x;
    if (node >= N_NODES) return;

    const unsigned slot = node + (node >> CSHIFT);
    unsigned e = boffs[slot];
    const unsigned o1 = boffs[slot + 1];
    float acc = 0.f;

    unsigned n0, n1, n2, n3, n4, n5, n6, n7;
    bool have = (e + 8 <= o1);
    if (have) {
        n0 = sorted[e];     n1 = sorted[e + 1]; n2 = sorted[e + 2]; n3 = sorted[e + 3];
        n4 = sorted[e + 4]; n5 = sorted[e + 5]; n6 = sorted[e + 6]; n7 = sorted[e + 7];
    }
    while (have) {
        unsigned c0 = n0, c1 = n1, c2 = n2, c3 = n3, c4 = n4, c5 = n5, c6 = n6, c7 = n7;
        e += 8;
        have = (e + 8 <= o1);
        if (have) {
            n0 = sorted[e];     n1 = sorted[e + 1]; n2 = sorted[e + 2]; n3 = sorted[e + 3];
            n4 = sorted[e + 4]; n5 = sorted[e + 5]; n6 = sorted[e + 6]; n7 = sorted[e + 7];
        }
        float t0 = tp[c0], t1 = tp[c1], t2 = tp[c2], t3 = tp[c3];
        float t4 = tp[c4], t5 = tp[c5], t6 = tp[c6], t7 = tp[c7];
        acc += t0 + t1 + t2 + t3;
        acc += t4 + t5 + t6 + t7;
    }
    for (; e < o1; ++e) acc += tp[sorted[e]];

    out[node] = fmaf(dinv[node], tp[node] + acc, b2[0]);
}

// ---------------- launch ----------------

extern "C" void kernel_launch(void* const* d_in, const int* in_sizes, int n_in,
                              void* d_out, int out_size, void* d_ws, size_t ws_size,
                              hipStream_t stream) {
    const float* x   = (const float*)d_in[0];
    const int*   ei  = (const int*)d_in[1];
    const float* W1  = (const float*)d_in[2];
    const float* b1  = (const float*)d_in[3];
    const float* W2  = (const float*)d_in[4];
    const float* b2  = (const float*)d_in[5];
    float* out = (float*)d_out;

    const int* row = ei;               // sources
    const int* col = ei + N_EDGES;     // targets

    // ws: [table NBLK*TW u16][boffs NSLOT][dinv N][tp N][h16 16N fp16]
    //     [tmp1 NBLK*SB1 u32][sorted NC*CAPB u32]
    unsigned short* table = (unsigned short*)d_ws;
    unsigned* boffs  = (unsigned*)d_ws + 153280;           // 782*392 u16 = 153272 u32, pad 8
    float*    dinv   = (float*)(boffs + NSLOT + 57);       // -> u32 offset 353920, 16B aligned
    float*    tp     = dinv + N_NODES;
    __half*   h16    = (__half*)(tp + N_NODES);
    unsigned* tmp1   = (unsigned*)(h16 + (size_t)N_NODES * HIDDEN);
    unsigned* sorted = tmp1 + (size_t)NBLK * SB1;

    k_cscat<<<NBLK, 512, 0, stream>>>(row, col, table, tmp1);
    k_bsort<<<NC, 1024, 0, stream>>>(tmp1, table, boffs, dinv, sorted);
    k_gemm1<<<(N_NODES / 16 + 3) / 4, 256, 0, stream>>>(x, W1, dinv, h16);
    k_agg1<<<(N_NODES * 8 + 255) / 256, 256, 0, stream>>>(sorted, boffs, (const uint2*)h16,
                                                          dinv, b1, W2, tp);
    k_agg2<<<(N_NODES + 255) / 256, 256, 0, stream>>>(sorted, boffs, tp, dinv, b2, out);
}

// Round 12
// 373.600 us; speedup vs baseline: 1.2797x; 1.2797x over previous
//
#include <hip/hip_runtime.h>
#include <hip/hip_fp16.h>

#define N_NODES 200000
#define N_EDGES 6400000
#define IN_FEAT 128
#define HIDDEN  16

// ---- bucket sort: LDS block-sort + dense run dump into padded bucket windows ----
#define RN 512
#define CSHIFT 9
#define NC 391                 // 391*512 = 200192 >= N_NODES
#define CAPB 18432             // bucket window cap (mean 16368, +16 sigma)
#define SRC_MASK 0x3FFFFu      // 18 bits, N_NODES < 262144
#define SB1 8192               // edges per cscat block
#define NBLK 782               // ceil(N_EDGES / SB1)
#define NSLOT (NC * (RN + 1))  // boffs slots; slot = node + (node>>CSHIFT)

typedef float v4f __attribute__((ext_vector_type(4)));
typedef _Float16 f16x8 __attribute__((ext_vector_type(8)));
typedef float f32x4 __attribute__((ext_vector_type(4)));

// ---------------- 0. init bucket bump pointers to window bases ----------------

__global__ void k_init(unsigned* __restrict__ ccur) {
    int b = blockIdx.x * 256 + threadIdx.x;
    if (b < NC) ccur[b] = (unsigned)b * CAPB;
}

// ------- 1. LDS block-sort, then dense per-bucket run dump (coalesced stores) -------

__global__ __launch_bounds__(512) void k_cscat(const int* __restrict__ row,
                                               const int* __restrict__ col,
                                               unsigned* __restrict__ ccur,
                                               unsigned* __restrict__ tmp1) {
    __shared__ unsigned cnt[512], s[512], cur[512], gdst[512];   // 8 KB
    __shared__ unsigned buf[SB1];                                // 32 KB
    __shared__ unsigned short bkt[SB1];                          // 16 KB
    const long long e0 = (long long)blockIdx.x * SB1;
    long long rem = (long long)N_EDGES - e0;
    const int n = rem > SB1 ? SB1 : (int)rem;   // multiple of 4
    const int t = threadIdx.x;
    cnt[t] = 0u;
    __syncthreads();

    // count pass (col only, int4)
    const int4* c4 = (const int4*)(col + e0);
    for (int i = t; i < n / 4; i += 512) {
        int4 v = c4[i];
        atomicAdd(&cnt[(unsigned)v.x >> CSHIFT], 1u);
        atomicAdd(&cnt[(unsigned)v.y >> CSHIFT], 1u);
        atomicAdd(&cnt[(unsigned)v.z >> CSHIFT], 1u);
        atomicAdd(&cnt[(unsigned)v.w >> CSHIFT], 1u);
    }
    __syncthreads();

    // inclusive scan over 512 -> exclusive bases
    unsigned cv = cnt[t];
    s[t] = cv;
    __syncthreads();
    #pragma unroll
    for (int d = 1; d < 512; d <<= 1) {
        unsigned add = (t >= d) ? s[t - d] : 0u;
        __syncthreads();
        s[t] += add;
        __syncthreads();
    }
    cur[t] = s[t] - cv;                         // exclusive prefix (local base)
    __syncthreads();

    // LDS scatter pass (re-read col/row, L2-hot) + bucket map
    for (int i = t; i < n; i += 512) {
        unsigned c = (unsigned)col[e0 + i];
        unsigned sr = (unsigned)row[e0 + i];
        unsigned b = c >> CSHIFT;
        unsigned pos = atomicAdd(&cur[b], 1u);
        buf[pos] = ((c & (RN - 1u)) << 18) | sr;
        bkt[pos] = (unsigned short)b;
    }
    // reserve global run space per bucket
    if (t < NC) gdst[t] = cnt[t] ? atomicAdd(&ccur[t], cnt[t]) : 0u;
    __syncthreads();

    // dense run dump: consecutive i in a run -> consecutive global dest
    for (int i = t; i < n; i += 512) {
        unsigned b = bkt[i];
        unsigned base = s[b] - cnt[b];
        unsigned dest = gdst[b] + ((unsigned)i - base);
        if (dest < (b + 1u) * CAPB) tmp1[dest] = buf[i];
    }
}

// ------- 2. per-bucket LDS-counter sort -> node-CSR + boffs + dinv -------
// boffs slot layout: bucket r owns slots [r*(RN+1), r*(RN+1)+RN]; slot = node + (node>>CSHIFT)

__global__ __launch_bounds__(1024) void k_bsort(const unsigned* __restrict__ tmp1,
                                                const unsigned* __restrict__ ccur,
                                                unsigned* __restrict__ boffs,
                                                float* __restrict__ dinv,
                                                unsigned* __restrict__ sorted) {
    __shared__ unsigned dcnt[RN], dcur[RN], sscan[RN];
    const int r = blockIdx.x;
    const unsigned lo = (unsigned)r * CAPB;
    unsigned fill = ccur[r] - lo;
    if (fill > CAPB) fill = CAPB;
    const unsigned hi = lo + fill;
    const unsigned node0 = (unsigned)r * RN;
    const unsigned slot0 = (unsigned)r * (RN + 1);
    if (threadIdx.x < RN) dcnt[threadIdx.x] = 0u;
    __syncthreads();

    for (unsigned i = lo + threadIdx.x; i < hi; i += 1024)
        atomicAdd(&dcnt[tmp1[i] >> 18], 1u);
    __syncthreads();

    unsigned c = 0;
    if (threadIdx.x < RN) { c = dcnt[threadIdx.x]; sscan[threadIdx.x] = c; }
    __syncthreads();
    #pragma unroll
    for (int d = 1; d < RN; d <<= 1) {
        unsigned add = 0;
        if (threadIdx.x < RN && threadIdx.x >= d) add = sscan[threadIdx.x - d];
        __syncthreads();
        if (threadIdx.x < RN) sscan[threadIdx.x] += add;
        __syncthreads();
    }
    if (threadIdx.x < RN) {
        unsigned excl = sscan[threadIdx.x] - c;
        dcur[threadIdx.x] = excl;
        boffs[slot0 + threadIdx.x] = lo + excl;
        unsigned node = node0 + threadIdx.x;
        if (node < N_NODES) dinv[node] = rsqrtf((float)c + 1.0f);   // +1 self-loop
    }
    if (threadIdx.x == 0) boffs[slot0 + RN] = hi;
    __syncthreads();

    unsigned i = lo + threadIdx.x;
    for (; i + 7168 < hi; i += 8192) {          // 8-deep ILP on atomic-return chains
        unsigned p0 = tmp1[i];
        unsigned p1 = tmp1[i + 1024];
        unsigned p2 = tmp1[i + 2048];
        unsigned p3 = tmp1[i + 3072];
        unsigned p4 = tmp1[i + 4096];
        unsigned p5 = tmp1[i + 5120];
        unsigned p6 = tmp1[i + 6144];
        unsigned p7 = tmp1[i + 7168];
        unsigned q0 = atomicAdd(&dcur[p0 >> 18], 1u);
        unsigned q1 = atomicAdd(&dcur[p1 >> 18], 1u);
        unsigned q2 = atomicAdd(&dcur[p2 >> 18], 1u);
        unsigned q3 = atomicAdd(&dcur[p3 >> 18], 1u);
        unsigned q4 = atomicAdd(&dcur[p4 >> 18], 1u);
        unsigned q5 = atomicAdd(&dcur[p5 >> 18], 1u);
        unsigned q6 = atomicAdd(&dcur[p6 >> 18], 1u);
        unsigned q7 = atomicAdd(&dcur[p7 >> 18], 1u);
        sorted[lo + q0] = p0 & SRC_MASK;
        sorted[lo + q1] = p1 & SRC_MASK;
        sorted[lo + q2] = p2 & SRC_MASK;
        sorted[lo + q3] = p3 & SRC_MASK;
        sorted[lo + q4] = p4 & SRC_MASK;
        sorted[lo + q5] = p5 & SRC_MASK;
        sorted[lo + q6] = p6 & SRC_MASK;
        sorted[lo + q7] = p7 & SRC_MASK;
    }
    for (; i < hi; i += 1024) {
        unsigned p = tmp1[i];
        unsigned pos = atomicAdd(&dcur[p >> 18], 1u);
        sorted[lo + pos] = p & SRC_MASK;
    }
}

// ---------------- layer-1 GEMM via MFMA: h16 = dinv .* (x @ W1), fp16 ----------------

__global__ __launch_bounds__(256) void k_gemm1(const float* __restrict__ x,
                                               const float* __restrict__ W1,
                                               const float* __restrict__ dinv,
                                               __half* __restrict__ h16) {
    const int wave = (blockIdx.x * 256 + threadIdx.x) >> 6;   // tile id
    const int lane = threadIdx.x & 63;
    const int m16 = lane & 15;
    const int quad = lane >> 4;
    if (wave * 16 >= N_NODES) return;

    f16x8 bf[4];
    #pragma unroll
    for (int kb = 0; kb < 4; ++kb)
        #pragma unroll
        for (int j = 0; j < 8; ++j)
            bf[kb][j] = (_Float16)W1[(kb * 32 + quad * 8 + j) * HIDDEN + m16];

    const int node0 = wave * 16;
    const float* xrow = x + (size_t)(node0 + m16) * IN_FEAT + quad * 8;
    f32x4 acc = {0.f, 0.f, 0.f, 0.f};
    #pragma unroll
    for (int kb = 0; kb < 4; ++kb) {
        const v4f* p = (const v4f*)(xrow + kb * 32);
        v4f u0 = p[0], u1 = p[1];
        f16x8 af;
        af[0] = (_Float16)u0.x; af[1] = (_Float16)u0.y;
        af[2] = (_Float16)u0.z; af[3] = (_Float16)u0.w;
        af[4] = (_Float16)u1.x; af[5] = (_Float16)u1.y;
        af[6] = (_Float16)u1.z; af[7] = (_Float16)u1.w;
        acc = __builtin_amdgcn_mfma_f32_16x16x32_f16(af, bf[kb], acc, 0, 0, 0);
    }
    #pragma unroll
    for (int r = 0; r < 4; ++r) {
        int node = node0 + quad * 4 + r;
        h16[(size_t)node * HIDDEN + m16] = __float2half(dinv[node] * acc[r]);
    }
}

// ------- layer-1 CSR aggregation: 8 lanes/node, uint2 pair-gather (16 edges in flight) -------
// lane l: q=l&3 owns features 4q..4q+3; eh=l>>2 owns edges of parity eh within each pair.

__global__ __launch_bounds__(256) void k_agg1(const unsigned* __restrict__ sorted,
                                              const unsigned* __restrict__ boffs,
                                              const uint2* __restrict__ h16v,
                                              const float* __restrict__ dinv,
                                              const float* __restrict__ b1,
                                              const float* __restrict__ W2,
                                              float* __restrict__ tp) {
    const unsigned tid = blockIdx.x * 256 + threadIdx.x;
    const unsigned node = tid >> 3;
    const int l = tid & 7;
    const int q = l & 3;
    const int eh = l >> 2;
    if (node >= N_NODES) return;

    const unsigned slot = node + (node >> CSHIFT);
    unsigned e = boffs[slot];
    const unsigned o1 = boffs[slot + 1];
    float a0 = 0.f, a1 = 0.f, a2 = 0.f, a3 = 0.f;

    unsigned nb0, nb1, nb2, nb3, nb4, nb5, nb6, nb7;
    bool have = (e + 16 <= o1);
    if (have) {
        nb0 = sorted[e +  0 + eh]; nb1 = sorted[e +  2 + eh];
        nb2 = sorted[e +  4 + eh]; nb3 = sorted[e +  6 + eh];
        nb4 = sorted[e +  8 + eh]; nb5 = sorted[e + 10 + eh];
        nb6 = sorted[e + 12 + eh]; nb7 = sorted[e + 14 + eh];
    }
    while (have) {
        unsigned cb0 = nb0, cb1 = nb1, cb2 = nb2, cb3 = nb3;
        unsigned cb4 = nb4, cb5 = nb5, cb6 = nb6, cb7 = nb7;
        e += 16;
        have = (e + 16 <= o1);
        if (have) {
            nb0 = sorted[e +  0 + eh]; nb1 = sorted[e +  2 + eh];
            nb2 = sorted[e +  4 + eh]; nb3 = sorted[e +  6 + eh];
            nb4 = sorted[e +  8 + eh]; nb5 = sorted[e + 10 + eh];
            nb6 = sorted[e + 12 + eh]; nb7 = sorted[e + 14 + eh];
        }
        uint2 v0 = h16v[(size_t)cb0 * 4 + q];
        uint2 v1 = h16v[(size_t)cb1 * 4 + q];
        uint2 v2 = h16v[(size_t)cb2 * 4 + q];
        uint2 v3 = h16v[(size_t)cb3 * 4 + q];
        uint2 v4 = h16v[(size_t)cb4 * 4 + q];
        uint2 v5 = h16v[(size_t)cb5 * 4 + q];
        uint2 v6 = h16v[(size_t)cb6 * 4 + q];
        uint2 v7 = h16v[(size_t)cb7 * 4 + q];
        float2 f, g;
        f = __half22float2(*(const __half2*)&v0.x); g = __half22float2(*(const __half2*)&v0.y);
        a0 += f.x; a1 += f.y; a2 += g.x; a3 += g.y;
        f = __half22float2(*(const __half2*)&v1.x); g = __half22float2(*(const __half2*)&v1.y);
        a0 += f.x; a1 += f.y; a2 += g.x; a3 += g.y;
        f = __half22float2(*(const __half2*)&v2.x); g = __half22float2(*(const __half2*)&v2.y);
        a0 += f.x; a1 += f.y; a2 += g.x; a3 += g.y;
        f = __half22float2(*(const __half2*)&v3.x); g = __half22float2(*(const __half2*)&v3.y);
        a0 += f.x; a1 += f.y; a2 += g.x; a3 += g.y;
        f = __half22float2(*(const __half2*)&v4.x); g = __half22float2(*(const __half2*)&v4.y);
        a0 += f.x; a1 += f.y; a2 += g.x; a3 += g.y;
        f = __half22float2(*(const __half2*)&v5.x); g = __half22float2(*(const __half2*)&v5.y);
        a0 += f.x; a1 += f.y; a2 += g.x; a3 += g.y;
        f = __half22float2(*(const __half2*)&v6.x); g = __half22float2(*(const __half2*)&v6.y);
        a0 += f.x; a1 += f.y; a2 += g.x; a3 += g.y;
        f = __half22float2(*(const __half2*)&v7.x); g = __half22float2(*(const __half2*)&v7.y);
        a0 += f.x; a1 += f.y; a2 += g.x; a3 += g.y;
    }
    if (e + 8 <= o1) {                           // mid block: 8 edges, 4 pair-slots
        unsigned cb0 = sorted[e + 0 + eh], cb1 = sorted[e + 2 + eh];
        unsigned cb2 = sorted[e + 4 + eh], cb3 = sorted[e + 6 + eh];
        uint2 v0 = h16v[(size_t)cb0 * 4 + q];
        uint2 v1 = h16v[(size_t)cb1 * 4 + q];
        uint2 v2 = h16v[(size_t)cb2 * 4 + q];
        uint2 v3 = h16v[(size_t)cb3 * 4 + q];
        float2 f, g;
        f = __half22float2(*(const __half2*)&v0.x); g = __half22float2(*(const __half2*)&v0.y);
        a0 += f.x; a1 += f.y; a2 += g.x; a3 += g.y;
        f = __half22float2(*(const __half2*)&v1.x); g = __half22float2(*(const __half2*)&v1.y);
        a0 += f.x; a1 += f.y; a2 += g.x; a3 += g.y;
        f = __half22float2(*(const __half2*)&v2.x); g = __half22float2(*(const __half2*)&v2.y);
        a0 += f.x; a1 += f.y; a2 += g.x; a3 += g.y;
        f = __half22float2(*(const __half2*)&v3.x); g = __half22float2(*(const __half2*)&v3.y);
        a0 += f.x; a1 += f.y; a2 += g.x; a3 += g.y;
        e += 8;
    }
    for (; e < o1; ++e) {                        // scalar tail: eh==0 half only
        if (eh == 0) {
            unsigned s = sorted[e];
            uint2 v = h16v[(size_t)s * 4 + q];
            float2 f = __half22float2(*(const __half2*)&v.x);
            float2 g = __half22float2(*(const __half2*)&v.y);
            a0 += f.x; a1 += f.y; a2 += g.x; a3 += g.y;
        }
    }

    // merge edge halves (lanes l and l^4 hold same features, complementary edges)
    a0 += __shfl_xor(a0, 4, 8);
    a1 += __shfl_xor(a1, 4, 8);
    a2 += __shfl_xor(a2, 4, 8);
    a3 += __shfl_xor(a3, 4, 8);

    // self-loop + node2 epilogue
    uint2 vs = h16v[(size_t)node * 4 + q];
    float2 s01 = __half22float2(*(const __half2*)&vs.x);
    float2 s23 = __half22float2(*(const __half2*)&vs.y);
    float di = dinv[node];
    float p0 = fmaf(di, a0 + s01.x, b1[4 * q + 0]);
    float p1 = fmaf(di, a1 + s01.y, b1[4 * q + 1]);
    float p2 = fmaf(di, a2 + s23.x, b1[4 * q + 2]);
    float p3 = fmaf(di, a3 + s23.y, b1[4 * q + 3]);
    float r = fmaxf(p0, 0.f) * W2[4 * q + 0] + fmaxf(p1, 0.f) * W2[4 * q + 1]
            + fmaxf(p2, 0.f) * W2[4 * q + 2] + fmaxf(p3, 0.f) * W2[4 * q + 3];
    r += __shfl_xor(r, 2, 8);
    r += __shfl_xor(r, 1, 8);
    if (l == 0) tp[node] = di * r;
}

// ------- layer-2 CSR aggregation (1 lane/node, 8-deep) + fused finalize -------

__global__ __launch_bounds__(256) void k_agg2(const unsigned* __restrict__ sorted,
                                              const unsigned* __restrict__ boffs,
                                              const float* __restrict__ tp,
                                              const float* __restrict__ dinv,
                                              const float* __restrict__ b2,
                                              float* __restrict__ out) {
    const unsigned node = blockIdx.x * 256 + threadIdx.x;
    if (node >= N_NODES) return;

    const unsigned slot = node + (node >> CSHIFT);
    unsigned e = boffs[slot];
    const unsigned o1 = boffs[slot + 1];
    float acc = 0.f;

    unsigned n0, n1, n2, n3, n4, n5, n6, n7;
    bool have = (e + 8 <= o1);
    if (have) {
        n0 = sorted[e];     n1 = sorted[e + 1]; n2 = sorted[e + 2]; n3 = sorted[e + 3];
        n4 = sorted[e + 4]; n5 = sorted[e + 5]; n6 = sorted[e + 6]; n7 = sorted[e + 7];
    }
    while (have) {
        unsigned c0 = n0, c1 = n1, c2 = n2, c3 = n3, c4 = n4, c5 = n5, c6 = n6, c7 = n7;
        e += 8;
        have = (e + 8 <= o1);
        if (have) {
            n0 = sorted[e];     n1 = sorted[e + 1]; n2 = sorted[e + 2]; n3 = sorted[e + 3];
            n4 = sorted[e + 4]; n5 = sorted[e + 5]; n6 = sorted[e + 6]; n7 = sorted[e + 7];
        }
        float t0 = tp[c0], t1 = tp[c1], t2 = tp[c2], t3 = tp[c3];
        float t4 = tp[c4], t5 = tp[c5], t6 = tp[c6], t7 = tp[c7];
        acc += t0 + t1 + t2 + t3;
        acc += t4 + t5 + t6 + t7;
    }
    for (; e < o1; ++e) acc += tp[sorted[e]];

    out[node] = fmaf(dinv[node], tp[node] + acc, b2[0]);
}

// ---------------- launch ----------------

extern "C" void kernel_launch(void* const* d_in, const int* in_sizes, int n_in,
                              void* d_out, int out_size, void* d_ws, size_t ws_size,
                              hipStream_t stream) {
    const float* x   = (const float*)d_in[0];
    const int*   ei  = (const int*)d_in[1];
    const float* W1  = (const float*)d_in[2];
    const float* b1  = (const float*)d_in[3];
    const float* W2  = (const float*)d_in[4];
    const float* b2  = (const float*)d_in[5];
    float* out = (float*)d_out;

    const int* row = ei;               // sources
    const int* col = ei + N_EDGES;     // targets

    // ws: [ccur 512][boffs NSLOT+pad][dinv N][tp N][h16 16N fp16][tmp1 NC*CAPB][sorted NC*CAPB]
    unsigned* ccur   = (unsigned*)d_ws;
    unsigned* boffs  = ccur + 512;
    float*    dinv   = (float*)(boffs + NSLOT + 73);       // +73 -> 200656, keeps 16B align
    float*    tp     = dinv + N_NODES;
    __half*   h16    = (__half*)(tp + N_NODES);
    unsigned* tmp1   = (unsigned*)(h16 + (size_t)N_NODES * HIDDEN);
    unsigned* sorted = tmp1 + (size_t)NC * CAPB;

    k_init<<<2, 256, 0, stream>>>(ccur);
    k_cscat<<<NBLK, 512, 0, stream>>>(row, col, ccur, tmp1);
    k_bsort<<<NC, 1024, 0, stream>>>(tmp1, ccur, boffs, dinv, sorted);
    k_gemm1<<<(N_NODES / 16 + 3) / 4, 256, 0, stream>>>(x, W1, dinv, h16);
    k_agg1<<<(N_NODES * 8 + 255) / 256, 256, 0, stream>>>(sorted, boffs, (const uint2*)h16,
                                                          dinv, b1, W2, tp);
    k_agg2<<<(N_NODES + 255) / 256, 256, 0, stream>>>(sorted, boffs, tp, dinv, b2, out);
}